// Round 8
// baseline (96.565 us; speedup 1.0000x reference)
//
#include <hip/hip_runtime.h>

#define N_  128
#define C_  256
#define T_  48
#define V_  25

typedef float v4f __attribute__((ext_vector_type(4)));

// ---------------- K1: row means. Pure read stream + tiny write. ----------------
// Block = 256 consecutive rows of 25 floats (6400 floats, contiguous, aligned).
__global__ __launch_bounds__(256) void k_rowmean(const float* __restrict__ x,
                                                 float* __restrict__ xbar) {
    __shared__ float xs[6400];
    const int tid = threadIdx.x;
    const float4* x4 = (const float4*)x;
    const unsigned base4 = blockIdx.x * 1600u;
    #pragma unroll
    for (int k = 0; k < 7; ++k) {
        int i4 = k * 256 + tid;
        if (i4 < 1600) ((float4*)xs)[i4] = x4[base4 + i4];
    }
    __syncthreads();
    float s = 0.f;
    #pragma unroll
    for (int v = 0; v < 25; ++v) s += xs[tid * 25 + v];   // stride 25: conflict-free
    xbar[blockIdx.x * 256u + tid] = s * 0.04f;
}

// ---------------- K2: gate math. Block = (n, half of T). ----------------
__global__ __launch_bounds__(256) void k_gate(const float* __restrict__ xbar,
    const float* __restrict__ wsq, const float* __restrict__ bsq,
    const float* __restrict__ gamma, const float* __restrict__ beta,
    const float* __restrict__ rmean, const float* __restrict__ rvar,
    const float* __restrict__ wc1, const float* __restrict__ bc1,
    const float* __restrict__ wex, const float* __restrict__ bex,
    float* __restrict__ gate) {
    __shared__ float xm[256 * 25];   // [c][k], stride 25, k<24 used
    __shared__ float ybn[384];       // [t][r]
    __shared__ float y1[384];        // [t][s]
    __shared__ float mv[384];        // [t][r]
    const int tid = threadIdx.x;
    const int n   = blockIdx.x >> 1;
    const int t0  = (blockIdx.x & 1) * 24;     // 24 % 3 == 0: segments don't cross halves
    // load xbar[n, :, t0..t0+23]
    for (int j = tid; j < 6144; j += 256) {
        int c = j / 24, k = j - c * 24;
        xm[c * 25 + k] = xbar[(unsigned)((n * 256 + c) * 48 + t0 + k)];
    }
    __syncthreads();
    // squeeze + BN: p = (t,r), 384 of them
    for (int p = tid; p < 384; p += 256) {
        int t = p >> 4, r = p & 15;
        float acc = 0.f;
        for (int c = 0; c < 256; ++c) acc += xm[c * 25 + t] * wsq[r * 256 + c];
        float sc = gamma[r] * rsqrtf(rvar[r] + 1e-5f);
        ybn[t * 16 + r] = (acc + bsq[r]) * sc + (beta[r] - rmean[r] * sc);
    }
    __syncthreads();
    // conv1
    for (int p = tid; p < 384; p += 256) {
        int t = p >> 4, s = p & 15;
        float acc = bc1[s];
        #pragma unroll
        for (int r = 0; r < 16; ++r) acc += ybn[t * 16 + r] * wc1[s * 16 + r];
        y1[t * 16 + s] = acc;
    }
    __syncthreads();
    // temporal diff (t0 multiple of 3 -> local t keeps phase)
    for (int p = tid; p < 384; p += 256) {
        int t = p >> 4, r = p & 15;
        mv[p] = ((t % 3) < 2) ? (y1[(t + 1) * 16 + r] - ybn[t * 16 + r]) : 0.f;
    }
    __syncthreads();
    // expand + sigmoid: thread = c
    {
        float wexr[16];
        #pragma unroll
        for (int r = 0; r < 16; ++r) wexr[r] = wex[tid * 16 + r];
        float be = bex[tid];
        float* gout = gate + (unsigned)((n * 256 + tid) * 48 + t0);
        #pragma unroll
        for (int t = 0; t < 24; ++t) {
            float a = be;
            #pragma unroll
            for (int r = 0; r < 16; ++r) a += mv[t * 16 + r] * wexr[r];
            gout[t] = 1.f / (1.f + expf(-a));
        }
    }
}

// ---------------- K3: apply. Pure grid-stride stream, no LDS, no barriers. ----------------
__global__ __launch_bounds__(256) void k_apply(const float* __restrict__ x,
                                               const float* __restrict__ gate,
                                               float* __restrict__ out) {
    const v4f* x4 = (const v4f*)x;
    v4f* o4 = (v4f*)out;
    const unsigned total4 = 9830400u;                 // N*C*T*V/4
    for (unsigned i4 = blockIdx.x * 256u + threadIdx.x; i4 < total4;
         i4 += 2048u * 256u) {
        v4f xv = x4[i4];
        unsigned i0 = i4 * 4u;
        unsigned r0 = i0 / 25u;                        // compiler magic-div
        unsigned j  = i0 - r0 * 25u;
        unsigned r3 = (j + 3u >= 25u) ? r0 + 1u : r0;
        float g0 = gate[r0];
        float g3 = gate[r3];
        v4f ov;
        ov.x = xv.x * g0;
        ov.y = xv.y * ((j + 1u < 25u) ? g0 : g3);
        ov.z = xv.z * ((j + 2u < 25u) ? g0 : g3);
        ov.w = xv.w * ((j + 3u < 25u) ? g0 : g3);
        __builtin_nontemporal_store(ov, &o4[i4]);      // out never re-read: keep x in L3
    }
}

extern "C" void kernel_launch(void* const* d_in, const int* in_sizes, int n_in,
                              void* d_out, int out_size, void* d_ws, size_t ws_size,
                              hipStream_t stream) {
    const float* x     = (const float*)d_in[0];
    const float* wsq   = (const float*)d_in[1];
    const float* bsq   = (const float*)d_in[2];
    const float* gamma = (const float*)d_in[3];
    const float* beta  = (const float*)d_in[4];
    const float* rmean = (const float*)d_in[5];
    const float* rvar  = (const float*)d_in[6];
    const float* wc1   = (const float*)d_in[7];
    const float* bc1   = (const float*)d_in[8];
    const float* wex   = (const float*)d_in[9];
    const float* bex   = (const float*)d_in[10];

    float* xbar = (float*)d_ws;                       // 1,572,864 floats
    float* gate = xbar + (size_t)N_ * C_ * T_;        // 1,572,864 floats

    k_rowmean<<<6144, 256, 0, stream>>>(x, xbar);
    k_gate<<<256, 256, 0, stream>>>(xbar, wsq, bsq, gamma, beta,
                                    rmean, rvar, wc1, bc1, wex, bex, gate);
    k_apply<<<2048, 256, 0, stream>>>(x, gate, (float*)d_out);
}